// Round 4
// baseline (373.460 us; speedup 1.0000x reference)
//
#include <hip/hip_runtime.h>
#include <type_traits>

typedef __attribute__((ext_vector_type(8))) short bf16x8;
typedef __attribute__((ext_vector_type(4))) float f32x4;

#define NB 8
#define NC 192
#define NO 576
#define NHW 16384
#define NH 6

__device__ __forceinline__ float bf2f(unsigned short u){
  return __uint_as_float(((unsigned int)u) << 16);
}
__device__ __forceinline__ unsigned short f2bf(float f){
  unsigned int u = __float_as_uint(f);
  u += 0x7FFFu + ((u >> 16) & 1u);   // RNE
  return (unsigned short)(u >> 16);
}

// convert fp32 -> bf16 (for qkv_w)
__global__ void cvt_w(const float* __restrict__ w, unsigned short* __restrict__ wb, int n4){
  const int i = blockIdx.x*256 + threadIdx.x;
  if (i < n4){
    float4 f = *(const float4*)(w + (long long)i*4);
    *(ushort4*)(wb + (long long)i*4) = make_ushort4(f2bf(f.x), f2bf(f.y), f2bf(f.z), f2bf(f.w));
  }
}

// out[b][o][n] = sum_c W[b?][o][c] * B[b][c][n],  K=192.
// W: bf16 k-contiguous, read straight from global (L2) as the SECOND mfma operand,
//    batched 6 frags/o-tile into regs before the k-loop.
// B (x/v): staged once per block into LDS (64 n-rows, transposed), FIRST operand.
// D: row=(lane>>4)*4+reg -> n (4 consecutive per lane => packed wide stores),
//    col=lane&15 -> o.
template<typename BT, typename OT>
__global__ __launch_bounds__(256) void gemm192v3(
    const unsigned short* __restrict__ W, long long w_bstride, int o_tiles,
    const BT* __restrict__ Bm, long long b_bstride,
    OT* __restrict__ Out, long long o_bstride)
{
  __shared__ __align__(16) unsigned short Xt[64 * 200];   // 25.6 KB
  const int t  = threadIdx.x;
  const int b  = blockIdx.z;
  const int n0 = blockIdx.x * 64;
  const BT* Bb = Bm + b_bstride * b;

  // stage x-tile transposed: Xt[n][c]; lane = n-row (write stride 100 dwords -> ~2-way)
  {
    const int n  = t & 63;
    const int cb = (t >> 6) * 48;
    #pragma unroll
    for (int j = 0; j < 12; ++j){
      const int c = cb + j*4;
      unsigned short u0,u1,u2,u3;
      if constexpr (std::is_same<BT,float>::value){
        u0 = f2bf(Bb[(long long)(c+0)*NHW + n0 + n]);
        u1 = f2bf(Bb[(long long)(c+1)*NHW + n0 + n]);
        u2 = f2bf(Bb[(long long)(c+2)*NHW + n0 + n]);
        u3 = f2bf(Bb[(long long)(c+3)*NHW + n0 + n]);
      } else {
        u0 = Bb[(long long)(c+0)*NHW + n0 + n];
        u1 = Bb[(long long)(c+1)*NHW + n0 + n];
        u2 = Bb[(long long)(c+2)*NHW + n0 + n];
        u3 = Bb[(long long)(c+3)*NHW + n0 + n];
      }
      *(ushort4*)&Xt[n*200 + c] = make_ushort4(u0,u1,u2,u3);
    }
  }
  __syncthreads();

  const int l  = t & 63;
  const int w  = t >> 6;    // wave id: owns o-stripe w*16 within each 64-o tile
  const int lr = l & 15;
  const int lg = l >> 4;

  const unsigned short* Wb = W + w_bstride * b;
  OT* ob = Out + o_bstride * b;

  for (int ot = 0; ot < o_tiles; ++ot){
    const int obase = ot*64 + w*16;
    const unsigned short* Wr = Wb + (long long)(obase + lr) * NC + lg*8;

    // batch all 6 weight fragments for this o-stripe (one L2 round trip)
    bf16x8 Bf[6];
    #pragma unroll
    for (int kk = 0; kk < 6; ++kk) Bf[kk] = *(const bf16x8*)(Wr + kk*32);

    f32x4 acc[4];
    #pragma unroll
    for (int i = 0; i < 4; ++i) acc[i] = (f32x4){0.f,0.f,0.f,0.f};

    #pragma unroll
    for (int kk = 0; kk < 6; ++kk){
      const int kc = kk*32 + lg*8;
      #pragma unroll
      for (int i = 0; i < 4; ++i){
        bf16x8 a = *(const bf16x8*)&Xt[(i*16 + lr)*200 + kc];
        acc[i] = __builtin_amdgcn_mfma_f32_16x16x32_bf16(a, Bf[kk], acc[i], 0,0,0);
      }
    }

    const long long o = obase + lr;          // col = lane&15 -> o
    #pragma unroll
    for (int i = 0; i < 4; ++i){
      const int n = n0 + i*16 + lg*4;        // row = (lane>>4)*4 + reg -> n (4 consecutive)
      if constexpr (std::is_same<OT, unsigned short>::value){
        uint2 p;
        p.x = (unsigned int)f2bf(acc[i][0]) | ((unsigned int)f2bf(acc[i][1]) << 16);
        p.y = (unsigned int)f2bf(acc[i][2]) | ((unsigned int)f2bf(acc[i][3]) << 16);
        *(uint2*)(ob + o*NHW + n) = p;
      } else {
        *(float4*)(ob + o*NHW + n) = make_float4(acc[i][0], acc[i][1], acc[i][2], acc[i][3]);
      }
    }
  }
}

// depthwise 3x3, SAME zero-pad. One block per (b,ch) image; thread owns an
// 8-wide column strip x 8 rows; rolling 3-row accumulators, halo via __shfl.
__global__ __launch_bounds__(256) void dwconv2(const unsigned short* __restrict__ pw,
    const float* __restrict__ wdw, unsigned short* __restrict__ outp,
    float* __restrict__ sumsq)
{
  const int ch = blockIdx.x;
  const int b  = blockIdx.y;
  const int t  = threadIdx.x;
  const int lane  = t & 63;
  const int strip = t & 15;        // column strip 0..15  (x0 = strip*8)
  const int y0    = (t >> 4) * 8;  // 16 row-groups x 8 rows = 128
  const int x0    = strip * 8;

  const long long choff = ((long long)b*NO + ch) << 14;
  const unsigned short* base = pw + choff;
  unsigned short* ob = outp + choff;

  float w[9];
  #pragma unroll
  for (int i=0;i<9;i++) w[i] = wdw[ch*9 + i];

  float a0[8], a1[8], a2[8];
  #pragma unroll
  for (int i=0;i<8;i++){ a0[i]=0.f; a1[i]=0.f; a2[i]=0.f; }
  float ss = 0.f;

  #pragma unroll
  for (int r = 0; r < 10; ++r){
    const int yy = y0 - 1 + r;
    float f[8];
    if (yy >= 0 && yy <= 127){
      uint4 u = *(const uint4*)(base + (yy << 7) + x0);
      f[0]=bf2f((unsigned short)(u.x&0xffff)); f[1]=bf2f((unsigned short)(u.x>>16));
      f[2]=bf2f((unsigned short)(u.y&0xffff)); f[3]=bf2f((unsigned short)(u.y>>16));
      f[4]=bf2f((unsigned short)(u.z&0xffff)); f[5]=bf2f((unsigned short)(u.z>>16));
      f[6]=bf2f((unsigned short)(u.w&0xffff)); f[7]=bf2f((unsigned short)(u.w>>16));
    } else {
      #pragma unroll
      for (int i=0;i<8;i++) f[i]=0.f;
    }
    // column halos from neighbor strips (same row-group => same yy)
    float lf = __shfl(f[7], lane - 1, 64);
    float rf = __shfl(f[0], lane + 1, 64);
    if (strip == 0)  lf = 0.f;
    if (strip == 15) rf = 0.f;

    #pragma unroll
    for (int i=0;i<8;i++){
      const float hL = (i==0) ? lf : f[i-1];
      const float hC = f[i];
      const float hR = (i==7) ? rf : f[i+1];
      a0[i] += w[6]*hL + w[7]*hC + w[8]*hR;   // -> output row yy-1 (dy=+1)
      a1[i] += w[3]*hL + w[4]*hC + w[5]*hR;   // -> output row yy   (dy= 0)
      a2[i] += w[0]*hL + w[1]*hC + w[2]*hR;   // -> output row yy+1 (dy=-1)
    }

    if (r >= 2){
      const int yo = y0 + r - 2;   // completed output row
      uint4 o;
      o.x = (unsigned int)f2bf(a0[0]) | ((unsigned int)f2bf(a0[1]) << 16);
      o.y = (unsigned int)f2bf(a0[2]) | ((unsigned int)f2bf(a0[3]) << 16);
      o.z = (unsigned int)f2bf(a0[4]) | ((unsigned int)f2bf(a0[5]) << 16);
      o.w = (unsigned int)f2bf(a0[6]) | ((unsigned int)f2bf(a0[7]) << 16);
      *(uint4*)(ob + (yo << 7) + x0) = o;
      #pragma unroll
      for (int i=0;i<8;i++) ss += a0[i]*a0[i];
    }
    // rotate
    #pragma unroll
    for (int i=0;i<8;i++){ a0[i]=a1[i]; a1[i]=a2[i]; a2[i]=0.f; }
  }

  if (ch < 384){
    #pragma unroll
    for (int off=32; off; off>>=1) ss += __shfl_down(ss, off);
    if (lane == 0) atomicAdd(&sumsq[b*384 + ch], ss);
  }
}

// raw q.k^T dots via MFMA straight from global; n-split x16 into partials
__global__ __launch_bounds__(256) void qkdots(const unsigned short* __restrict__ dw,
                                              float* __restrict__ partial)
{
  const int bh = blockIdx.x, ns = blockIdx.y;
  const int b = bh / 6, h = bh - b*6;
  const int t = threadIdx.x, w = t >> 6, l = t & 63, lr = l & 15, lg = l >> 4;
  const unsigned short* qb = dw + ((long long)b*NO + h*32) * NHW;
  const unsigned short* kb = dw + ((long long)b*NO + 192 + h*32) * NHW;
  const int nb = ns*1024 + w*256;
  f32x4 acc00 = {0.f,0.f,0.f,0.f}, acc01 = {0.f,0.f,0.f,0.f};
  f32x4 acc10 = {0.f,0.f,0.f,0.f}, acc11 = {0.f,0.f,0.f,0.f};
  #pragma unroll
  for (int kk=0; kk<8; kk++){
    const int n = nb + kk*32 + lg*8;
    bf16x8 a0 = *(const bf16x8*)(qb + (long long)(     lr)*NHW + n);
    bf16x8 a1 = *(const bf16x8*)(qb + (long long)(16 + lr)*NHW + n);
    bf16x8 b0 = *(const bf16x8*)(kb + (long long)(     lr)*NHW + n);
    bf16x8 b1 = *(const bf16x8*)(kb + (long long)(16 + lr)*NHW + n);
    acc00 = __builtin_amdgcn_mfma_f32_16x16x32_bf16(a0, b0, acc00, 0,0,0);
    acc01 = __builtin_amdgcn_mfma_f32_16x16x32_bf16(a0, b1, acc01, 0,0,0);
    acc10 = __builtin_amdgcn_mfma_f32_16x16x32_bf16(a1, b0, acc10, 0,0,0);
    acc11 = __builtin_amdgcn_mfma_f32_16x16x32_bf16(a1, b1, acc11, 0,0,0);
  }
  __shared__ float pl[4][32][32];
  #pragma unroll
  for (int r=0;r<4;r++){
    pl[w][ 0 + lg*4 + r][ 0 + lr] = acc00[r];
    pl[w][ 0 + lg*4 + r][16 + lr] = acc01[r];
    pl[w][16 + lg*4 + r][ 0 + lr] = acc10[r];
    pl[w][16 + lg*4 + r][16 + lr] = acc11[r];
  }
  __syncthreads();
  for (int e=t; e<1024; e+=256){
    const int r = e >> 5, c = e & 31;
    partial[((long long)bh*16 + ns)*1024 + e] = pl[0][r][c] + pl[1][r][c] + pl[2][r][c] + pl[3][r][c];
  }
}

__global__ __launch_bounds__(256) void softmaxk(const float* __restrict__ partial,
    const float* __restrict__ sumsq, const float* __restrict__ temp,
    float* __restrict__ attn)
{
  const int bh = blockIdx.x, b = bh / 6, h = bh - b*6;
  const int t = threadIdx.x;
  __shared__ float L[32][33];
  for (int e=t; e<1024; e+=256){
    const int c = e >> 5, d = e & 31;
    float s = 0.f;
    #pragma unroll
    for (int i=0;i<16;i++) s += partial[((long long)bh*16 + i)*1024 + e];
    const float nq = fmaxf(sqrtf(sumsq[b*384 + h*32 + c]),        1e-12f);
    const float nk = fmaxf(sqrtf(sumsq[b*384 + 192 + h*32 + d]),  1e-12f);
    L[c][d] = s / (nq * nk) * temp[h];
  }
  __syncthreads();
  if (t < 32){
    float m = -1e30f;
    #pragma unroll
    for (int d=0; d<32; d++) m = fmaxf(m, L[t][d]);
    float e[32]; float sum = 0.f;
    #pragma unroll
    for (int d=0; d<32; d++){ e[d] = expf(L[t][d] - m); sum += e[d]; }
    const float inv = 1.f / sum;
    #pragma unroll
    for (int d=0; d<32; d++) attn[(long long)bh*1024 + t*32 + d] = e[d] * inv;
  }
}

// Mcomb[b][o][h*32+d] = sum_c proj[o][h*32+c] * attn[b][h][c][d]
__global__ void mcombk(const float* __restrict__ proj, const float* __restrict__ attn,
                       unsigned short* __restrict__ mc)
{
  const int b = blockIdx.x, o = blockIdx.y, d = threadIdx.x;
  const int h = d >> 5, d32 = d & 31;
  const float* pr = proj + o*NC + h*32;
  const float* at = attn + ((long long)(b*NH + h))*1024 + d32;
  float acc = 0.f;
  #pragma unroll
  for (int c=0;c<32;c++) acc += pr[c] * at[c*32];
  mc[((long long)b*NC + o)*NC + d] = f2bf(acc);
}

extern "C" void kernel_launch(void* const* d_in, const int* in_sizes, int n_in,
                              void* d_out, int out_size, void* d_ws, size_t ws_size,
                              hipStream_t stream) {
  const float* x         = (const float*)d_in[0];
  const float* qkv_w     = (const float*)d_in[1];
  const float* qkv_dw_w  = (const float*)d_in[2];
  const float* proj_w    = (const float*)d_in[3];
  const float* temp      = (const float*)d_in[4];
  float* out = (float*)d_out;

  char* ws = (char*)d_ws;
  const size_t off_pw = 0;                                   // bf16 qkv pointwise
  const size_t off_dw = (size_t)NB*NO*NHW*2;                 // bf16 qkv depthwise (q|k|v)
  const size_t off_ss = off_dw + (size_t)NB*NO*NHW*2;        // fp32 sumsq [8][384]
  const size_t off_pp = off_ss + (size_t)NB*384*4;           // fp32 qk partials [48][16][1024]
  const size_t off_at = off_pp + (size_t)48*16*1024*4;       // fp32 attn [48][32][32]
  const size_t off_mc = off_at + (size_t)48*1024*4;          // bf16 Mcomb [8][192][192]
  const size_t off_wb = off_mc + (size_t)NB*NC*NC*2;         // bf16 qkv_w [576][192]

  unsigned short* pw     = (unsigned short*)(ws + off_pw);
  unsigned short* dwp    = (unsigned short*)(ws + off_dw);
  float*          sumsq  = (float*)(ws + off_ss);
  float*          partial= (float*)(ws + off_pp);
  float*          attn   = (float*)(ws + off_at);
  unsigned short* mcomb  = (unsigned short*)(ws + off_mc);
  unsigned short* wb     = (unsigned short*)(ws + off_wb);

  hipMemsetAsync(sumsq, 0, (size_t)NB*384*sizeof(float), stream);

  // 0) qkv_w -> bf16 (L2-resident weight for direct-from-global fragments)
  cvt_w<<<dim3((NO*NC/4 + 255)/256), 256, 0, stream>>>(qkv_w, wb, NO*NC/4);

  // 1) qkv pointwise: pw[b][o][n] = sum_c wb[o][c] x[b][c][n]
  gemm192v3<float, unsigned short><<<dim3(256,1,NB), 256, 0, stream>>>(
      wb, 0LL, 9, x, (long long)NC*NHW, pw, (long long)NO*NHW);

  // 2) depthwise 3x3 + sumsq for q,k rows
  dwconv2<<<dim3(NO, NB), 256, 0, stream>>>(pw, qkv_dw_w, dwp, sumsq);

  // 3) raw q.k^T partial dots
  qkdots<<<dim3(48,16), 256, 0, stream>>>(dwp, partial);

  // 4) normalize + temperature + softmax
  softmaxk<<<48, 256, 0, stream>>>(partial, sumsq, temp, attn);

  // 5) Mcomb = proj_w @ blockdiag(attn)
  mcombk<<<dim3(NB,192), 192, 0, stream>>>(proj_w, attn, mcomb);

  // 6) out = Mcomb @ v
  gemm192v3<unsigned short, float><<<dim3(256,1,NB), 256, 0, stream>>>(
      mcomb, (long long)NC*NC, 3, dwp + (long long)384*NHW, (long long)NO*NHW,
      out, (long long)NC*NHW);
}

// Round 6
// 370.961 us; speedup vs baseline: 1.0067x; 1.0067x over previous
//
#include <hip/hip_runtime.h>
#include <type_traits>

typedef __attribute__((ext_vector_type(8))) short bf16x8;
typedef __attribute__((ext_vector_type(4))) float f32x4;

#define NB 8
#define NC 192
#define NO 576
#define NHW 16384
#define NH 6

__device__ __forceinline__ float bf2f(unsigned short u){
  return __uint_as_float(((unsigned int)u) << 16);
}
__device__ __forceinline__ unsigned short f2bf(float f){
  unsigned int u = __float_as_uint(f);
  u += 0x7FFFu + ((u >> 16) & 1u);   // RNE
  return (unsigned short)(u >> 16);
}

// convert fp32 -> bf16 (for qkv_w)
__global__ void cvt_w(const float* __restrict__ w, unsigned short* __restrict__ wb, int n4){
  const int i = blockIdx.x*256 + threadIdx.x;
  if (i < n4){
    float4 f = *(const float4*)(w + (long long)i*4);
    *(ushort4*)(wb + (long long)i*4) = make_ushort4(f2bf(f.x), f2bf(f.y), f2bf(f.z), f2bf(f.w));
  }
}

// XOR chunk swizzle: 16B chunks (8 ushorts) within a 192-c row; closed on [0,24).
__device__ __forceinline__ int eswz(int n){ return ((n >> 3) ^ n) & 7; }

// out[b][o][n] = sum_c W[b?][o][c] * B[b][c][n],  K=192, o-tiles of 64 looped inside.
// W: bf16 k-contiguous straight from global (L2) as SECOND mfma operand.
// B (x/v): staged once per block into LDS (64 n-rows, transposed, XOR-swizzled).
// D: row=(lane>>4)*4+reg -> n (4 consecutive per lane => packed stores), col=lane&15 -> o.
template<typename BT, typename OT>
__global__ __launch_bounds__(256) void gemm192v4(
    const unsigned short* __restrict__ W, long long w_bstride, int o_tiles,
    const BT* __restrict__ Bm, long long b_bstride,
    OT* __restrict__ Out, long long o_bstride)
{
  __shared__ __align__(16) unsigned short Xt[64 * 200];   // 25.6 KB, 400B rows
  const int t  = threadIdx.x;
  const int b  = blockIdx.z;
  const int n0 = blockIdx.x * 64;
  const BT* Bb = Bm + b_bstride * b;

  // stage x-tile transposed: logical Xt[n][c], physical chunk = cc ^ eswz(n).
  // 768 cells = 48 c-quads x 16 n-quads; 3 cells/thread; 16B loads, 8B LDS writes.
  #pragma unroll
  for (int kci = 0; kci < 3; ++kci){
    const int cell = t + kci*256;
    const int nq = (cell & 15) * 4;        // n-quad base
    const int cq = cell >> 4;              // c-quad index 0..47
    const int cb = cq * 4;
    const int cc = cq >> 1;                // 16B chunk index 0..23
    const int h4 = (cq & 1) * 4;           // half-chunk offset (ushorts)

    float v[4][4];                         // [ci][nj]
    if constexpr (std::is_same<BT,float>::value){
      #pragma unroll
      for (int ci = 0; ci < 4; ++ci){
        float4 f = *(const float4*)(Bb + (long long)(cb+ci)*NHW + n0 + nq);
        v[ci][0]=f.x; v[ci][1]=f.y; v[ci][2]=f.z; v[ci][3]=f.w;
      }
      #pragma unroll
      for (int nj = 0; nj < 4; ++nj){
        const int n = nq + nj;
        ushort4 wv = make_ushort4(f2bf(v[0][nj]), f2bf(v[1][nj]), f2bf(v[2][nj]), f2bf(v[3][nj]));
        *(ushort4*)&Xt[n*200 + ((cc ^ eswz(n)) << 3) + h4] = wv;
      }
    } else {
      ushort4 u[4];
      #pragma unroll
      for (int ci = 0; ci < 4; ++ci)
        u[ci] = *(const ushort4*)(Bb + (long long)(cb+ci)*NHW + n0 + nq);
      const ushort4 w0 = make_ushort4(u[0].x, u[1].x, u[2].x, u[3].x);
      const ushort4 w1 = make_ushort4(u[0].y, u[1].y, u[2].y, u[3].y);
      const ushort4 w2 = make_ushort4(u[0].z, u[1].z, u[2].z, u[3].z);
      const ushort4 w3 = make_ushort4(u[0].w, u[1].w, u[2].w, u[3].w);
      *(ushort4*)&Xt[(nq+0)*200 + ((cc ^ eswz(nq+0)) << 3) + h4] = w0;
      *(ushort4*)&Xt[(nq+1)*200 + ((cc ^ eswz(nq+1)) << 3) + h4] = w1;
      *(ushort4*)&Xt[(nq+2)*200 + ((cc ^ eswz(nq+2)) << 3) + h4] = w2;
      *(ushort4*)&Xt[(nq+3)*200 + ((cc ^ eswz(nq+3)) << 3) + h4] = w3;
    }
  }
  __syncthreads();

  const int l  = t & 63;
  const int w  = t >> 6;    // wave id: owns o-stripe w*16 within each 64-o tile
  const int lr = l & 15;
  const int lg = l >> 4;

  const unsigned short* Wb = W + w_bstride * b;
  OT* ob = Out + o_bstride * b;

  // per-row physical chunk bases for this lane's 4 A-frag rows (rows i*16+lr)
  int rowoff[4], rowe[4];
  #pragma unroll
  for (int i = 0; i < 4; ++i){
    const int r = i*16 + lr;
    rowoff[i] = r * 200;
    rowe[i]   = eswz(r);
  }

  for (int ot = 0; ot < o_tiles; ++ot){
    const int obase = ot*64 + w*16;
    const unsigned short* Wr = Wb + (long long)(obase + lr) * NC + lg*8;

    // all 6 weight fragments for this o-stripe (one L2 round trip)
    bf16x8 Bf[6];
    #pragma unroll
    for (int kk = 0; kk < 6; ++kk) Bf[kk] = *(const bf16x8*)(Wr + kk*32);

    f32x4 acc[4];
    #pragma unroll
    for (int i = 0; i < 4; ++i) acc[i] = (f32x4){0.f,0.f,0.f,0.f};

    #pragma unroll
    for (int kk = 0; kk < 6; ++kk){
      const int cc = kk*4 + lg;            // logical 16B chunk of this k-slice
      #pragma unroll
      for (int i = 0; i < 4; ++i){
        bf16x8 a = *(const bf16x8*)&Xt[rowoff[i] + ((cc ^ rowe[i]) << 3)];
        acc[i] = __builtin_amdgcn_mfma_f32_16x16x32_bf16(a, Bf[kk], acc[i], 0,0,0);
      }
    }

    const long long o = obase + lr;        // col = lane&15 -> o
    #pragma unroll
    for (int i = 0; i < 4; ++i){
      const int n = n0 + i*16 + lg*4;      // row = (lane>>4)*4 + reg -> n (4 consecutive)
      if constexpr (std::is_same<OT, unsigned short>::value){
        uint2 p;
        p.x = (unsigned int)f2bf(acc[i][0]) | ((unsigned int)f2bf(acc[i][1]) << 16);
        p.y = (unsigned int)f2bf(acc[i][2]) | ((unsigned int)f2bf(acc[i][3]) << 16);
        *(uint2*)(ob + o*NHW + n) = p;
      } else {
        *(float4*)(ob + o*NHW + n) = make_float4(acc[i][0], acc[i][1], acc[i][2], acc[i][3]);
      }
    }
  }
}

// depthwise 3x3, SAME zero-pad. One block per (b,ch) image; thread owns an
// 8-wide column strip x 8 rows; rolling 3-row accumulators, halo via __shfl.
__global__ __launch_bounds__(256) void dwconv2(const unsigned short* __restrict__ pw,
    const float* __restrict__ wdw, unsigned short* __restrict__ outp,
    float* __restrict__ sumsq)
{
  const int ch = blockIdx.x;
  const int b  = blockIdx.y;
  const int t  = threadIdx.x;
  const int lane  = t & 63;
  const int strip = t & 15;        // column strip 0..15  (x0 = strip*8)
  const int y0    = (t >> 4) * 8;  // 16 row-groups x 8 rows = 128
  const int x0    = strip * 8;

  const long long choff = ((long long)b*NO + ch) << 14;
  const unsigned short* base = pw + choff;
  unsigned short* ob = outp + choff;

  float w[9];
  #pragma unroll
  for (int i=0;i<9;i++) w[i] = wdw[ch*9 + i];

  float a0[8], a1[8], a2[8];
  #pragma unroll
  for (int i=0;i<8;i++){ a0[i]=0.f; a1[i]=0.f; a2[i]=0.f; }
  float ss = 0.f;

  #pragma unroll
  for (int r = 0; r < 10; ++r){
    const int yy = y0 - 1 + r;
    float f[8];
    if (yy >= 0 && yy <= 127){
      uint4 u = *(const uint4*)(base + (yy << 7) + x0);
      f[0]=bf2f((unsigned short)(u.x&0xffff)); f[1]=bf2f((unsigned short)(u.x>>16));
      f[2]=bf2f((unsigned short)(u.y&0xffff)); f[3]=bf2f((unsigned short)(u.y>>16));
      f[4]=bf2f((unsigned short)(u.z&0xffff)); f[5]=bf2f((unsigned short)(u.z>>16));
      f[6]=bf2f((unsigned short)(u.w&0xffff)); f[7]=bf2f((unsigned short)(u.w>>16));
    } else {
      #pragma unroll
      for (int i=0;i<8;i++) f[i]=0.f;
    }
    // column halos from neighbor strips (same row-group => same yy)
    float lf = __shfl(f[7], lane - 1, 64);
    float rf = __shfl(f[0], lane + 1, 64);
    if (strip == 0)  lf = 0.f;
    if (strip == 15) rf = 0.f;

    #pragma unroll
    for (int i=0;i<8;i++){
      const float hL = (i==0) ? lf : f[i-1];
      const float hC = f[i];
      const float hR = (i==7) ? rf : f[i+1];
      a0[i] += w[6]*hL + w[7]*hC + w[8]*hR;   // -> output row yy-1 (dy=+1)
      a1[i] += w[3]*hL + w[4]*hC + w[5]*hR;   // -> output row yy   (dy= 0)
      a2[i] += w[0]*hL + w[1]*hC + w[2]*hR;   // -> output row yy+1 (dy=-1)
    }

    if (r >= 2){
      const int yo = y0 + r - 2;   // completed output row
      uint4 o;
      o.x = (unsigned int)f2bf(a0[0]) | ((unsigned int)f2bf(a0[1]) << 16);
      o.y = (unsigned int)f2bf(a0[2]) | ((unsigned int)f2bf(a0[3]) << 16);
      o.z = (unsigned int)f2bf(a0[4]) | ((unsigned int)f2bf(a0[5]) << 16);
      o.w = (unsigned int)f2bf(a0[6]) | ((unsigned int)f2bf(a0[7]) << 16);
      *(uint4*)(ob + (yo << 7) + x0) = o;
      #pragma unroll
      for (int i=0;i<8;i++) ss += a0[i]*a0[i];
    }
    // rotate
    #pragma unroll
    for (int i=0;i<8;i++){ a0[i]=a1[i]; a1[i]=a2[i]; a2[i]=0.f; }
  }

  if (ch < 384){
    #pragma unroll
    for (int off=32; off; off>>=1) ss += __shfl_down(ss, off);
    if (lane == 0) atomicAdd(&sumsq[b*384 + ch], ss);
  }
}

// raw q.k^T dots via MFMA straight from global; n-split x16 into partials
__global__ __launch_bounds__(256) void qkdots(const unsigned short* __restrict__ dw,
                                              float* __restrict__ partial)
{
  const int bh = blockIdx.x, ns = blockIdx.y;
  const int b = bh / 6, h = bh - b*6;
  const int t = threadIdx.x, w = t >> 6, l = t & 63, lr = l & 15, lg = l >> 4;
  const unsigned short* qb = dw + ((long long)b*NO + h*32) * NHW;
  const unsigned short* kb = dw + ((long long)b*NO + 192 + h*32) * NHW;
  const int nb = ns*1024 + w*256;
  f32x4 acc00 = {0.f,0.f,0.f,0.f}, acc01 = {0.f,0.f,0.f,0.f};
  f32x4 acc10 = {0.f,0.f,0.f,0.f}, acc11 = {0.f,0.f,0.f,0.f};
  #pragma unroll
  for (int kk=0; kk<8; kk++){
    const int n = nb + kk*32 + lg*8;
    bf16x8 a0 = *(const bf16x8*)(qb + (long long)(     lr)*NHW + n);
    bf16x8 a1 = *(const bf16x8*)(qb + (long long)(16 + lr)*NHW + n);
    bf16x8 b0 = *(const bf16x8*)(kb + (long long)(     lr)*NHW + n);
    bf16x8 b1 = *(const bf16x8*)(kb + (long long)(16 + lr)*NHW + n);
    acc00 = __builtin_amdgcn_mfma_f32_16x16x32_bf16(a0, b0, acc00, 0,0,0);
    acc01 = __builtin_amdgcn_mfma_f32_16x16x32_bf16(a0, b1, acc01, 0,0,0);
    acc10 = __builtin_amdgcn_mfma_f32_16x16x32_bf16(a1, b0, acc10, 0,0,0);
    acc11 = __builtin_amdgcn_mfma_f32_16x16x32_bf16(a1, b1, acc11, 0,0,0);
  }
  __shared__ float pl[4][32][32];
  #pragma unroll
  for (int r=0;r<4;r++){
    pl[w][ 0 + lg*4 + r][ 0 + lr] = acc00[r];
    pl[w][ 0 + lg*4 + r][16 + lr] = acc01[r];
    pl[w][16 + lg*4 + r][ 0 + lr] = acc10[r];
    pl[w][16 + lg*4 + r][16 + lr] = acc11[r];
  }
  __syncthreads();
  for (int e=t; e<1024; e+=256){
    const int r = e >> 5, c = e & 31;
    partial[((long long)bh*16 + ns)*1024 + e] = pl[0][r][c] + pl[1][r][c] + pl[2][r][c] + pl[3][r][c];
  }
}

__global__ __launch_bounds__(256) void softmaxk(const float* __restrict__ partial,
    const float* __restrict__ sumsq, const float* __restrict__ temp,
    float* __restrict__ attn)
{
  const int bh = blockIdx.x, b = bh / 6, h = bh - b*6;
  const int t = threadIdx.x;
  __shared__ float L[32][33];
  for (int e=t; e<1024; e+=256){
    const int c = e >> 5, d = e & 31;
    float s = 0.f;
    #pragma unroll
    for (int i=0;i<16;i++) s += partial[((long long)bh*16 + i)*1024 + e];
    const float nq = fmaxf(sqrtf(sumsq[b*384 + h*32 + c]),        1e-12f);
    const float nk = fmaxf(sqrtf(sumsq[b*384 + 192 + h*32 + d]),  1e-12f);
    L[c][d] = s / (nq * nk) * temp[h];
  }
  __syncthreads();
  if (t < 32){
    float m = -1e30f;
    #pragma unroll
    for (int d=0; d<32; d++) m = fmaxf(m, L[t][d]);
    float e[32]; float sum = 0.f;
    #pragma unroll
    for (int d=0; d<32; d++){ e[d] = expf(L[t][d] - m); sum += e[d]; }
    const float inv = 1.f / sum;
    #pragma unroll
    for (int d=0; d<32; d++) attn[(long long)bh*1024 + t*32 + d] = e[d] * inv;
  }
}

// Mcomb[b][o][h*32+d] = sum_c proj[o][h*32+c] * attn[b][h][c][d]
__global__ void mcombk(const float* __restrict__ proj, const float* __restrict__ attn,
                       unsigned short* __restrict__ mc)
{
  const int b = blockIdx.x, o = blockIdx.y, d = threadIdx.x;
  const int h = d >> 5, d32 = d & 31;
  const float* pr = proj + o*NC + h*32;
  const float* at = attn + ((long long)(b*NH + h))*1024 + d32;
  float acc = 0.f;
  #pragma unroll
  for (int c=0;c<32;c++) acc += pr[c] * at[c*32];
  mc[((long long)b*NC + o)*NC + d] = f2bf(acc);
}

extern "C" void kernel_launch(void* const* d_in, const int* in_sizes, int n_in,
                              void* d_out, int out_size, void* d_ws, size_t ws_size,
                              hipStream_t stream) {
  const float* x         = (const float*)d_in[0];
  const float* qkv_w     = (const float*)d_in[1];
  const float* qkv_dw_w  = (const float*)d_in[2];
  const float* proj_w    = (const float*)d_in[3];
  const float* temp      = (const float*)d_in[4];
  float* out = (float*)d_out;

  char* ws = (char*)d_ws;
  const size_t off_pw = 0;                                   // bf16 qkv pointwise
  const size_t off_dw = (size_t)NB*NO*NHW*2;                 // bf16 qkv depthwise (q|k|v)
  const size_t off_ss = off_dw + (size_t)NB*NO*NHW*2;        // fp32 sumsq [8][384]
  const size_t off_pp = off_ss + (size_t)NB*384*4;           // fp32 qk partials [48][16][1024]
  const size_t off_at = off_pp + (size_t)48*16*1024*4;       // fp32 attn [48][32][32]
  const size_t off_mc = off_at + (size_t)48*1024*4;          // bf16 Mcomb [8][192][192]
  const size_t off_wb = off_mc + (size_t)NB*NC*NC*2;         // bf16 qkv_w [576][192]

  unsigned short* pw     = (unsigned short*)(ws + off_pw);
  unsigned short* dwp    = (unsigned short*)(ws + off_dw);
  float*          sumsq  = (float*)(ws + off_ss);
  float*          partial= (float*)(ws + off_pp);
  float*          attn   = (float*)(ws + off_at);
  unsigned short* mcomb  = (unsigned short*)(ws + off_mc);
  unsigned short* wb     = (unsigned short*)(ws + off_wb);

  hipMemsetAsync(sumsq, 0, (size_t)NB*384*sizeof(float), stream);

  // 0) qkv_w -> bf16 (L2-resident weight for direct-from-global fragments)
  cvt_w<<<dim3((NO*NC/4 + 255)/256), 256, 0, stream>>>(qkv_w, wb, NO*NC/4);

  // 1) qkv pointwise: pw[b][o][n] = sum_c wb[o][c] x[b][c][n]
  gemm192v4<float, unsigned short><<<dim3(256,1,NB), 256, 0, stream>>>(
      wb, 0LL, 9, x, (long long)NC*NHW, pw, (long long)NO*NHW);

  // 2) depthwise 3x3 + sumsq for q,k rows
  dwconv2<<<dim3(NO, NB), 256, 0, stream>>>(pw, qkv_dw_w, dwp, sumsq);

  // 3) raw q.k^T partial dots
  qkdots<<<dim3(48,16), 256, 0, stream>>>(dwp, partial);

  // 4) normalize + temperature + softmax
  softmaxk<<<48, 256, 0, stream>>>(partial, sumsq, temp, attn);

  // 5) Mcomb = proj_w @ blockdiag(attn)
  mcombk<<<dim3(NB,192), 192, 0, stream>>>(proj_w, attn, mcomb);

  // 6) out = Mcomb @ v
  gemm192v4<unsigned short, float><<<dim3(256,1,NB), 256, 0, stream>>>(
      mcomb, (long long)NC*NC, 3, dwp + (long long)384*NHW, (long long)NO*NHW,
      out, (long long)NC*NHW);
}